// Round 4
// baseline (50.383 us; speedup 1.0000x reference)
//
#include <hip/hip_runtime.h>

// Problem shape (fixed by the reference setup)
#define TT 512
#define BB 32
#define FF 256
#define LL 8
#define NCHAIN (BB * FF * LL)   // 65536 chains
#define NGROUP (NCHAIN / 4)     // 16384 float4 groups (4 consecutive l's)

typedef float f32x4 __attribute__((ext_vector_type(4)));

// Decomposition (both kernels): 64 blocks of 256 per chunk.
// blockLocal = blockIdx & 63; b = blockLocal>>1 (block-uniform -> resets is a
// scalar broadcast); idx = ((blockLocal&1)<<8)|tid; f = idx>>1; h = idx&1;
// group g = (b<<9)|idx. Consecutive lanes -> consecutive 16B slots -> 1KiB/wave.

// Kernel 1: zero-init chunk scan. Writes E_t (scan with s0=0) straight into
// the ys output stream, plus the chunk summary (A = prod of a_t, E_end).
// True value is y_t = E_t + P_t*s0 with P_t = lam^(t+1) before the chunk's
// first reset and 0 after -> kernel 2 applies that tiny correction.
template <int NCHUNK>
__global__ __launch_bounds__(256) void scan_write_kernel(
    const float* __restrict__ features,  // [T,B,F]
    const int*   __restrict__ resets,    // [T,B]
    const float* __restrict__ lambdas,   // [L]
    f32x4*       __restrict__ wsA,       // [NCHUNK][NGROUP]
    f32x4*       __restrict__ wsE,       // [NCHUNK][NGROUP]
    f32x4*       __restrict__ out4)      // [NGROUP] final, then [T][NGROUP]
{
    constexpr int TC = TT / NCHUNK;
    const int chunk      = blockIdx.x >> 6;
    const int blockLocal = blockIdx.x & 63;
    const int b   = blockLocal >> 1;
    const int idx = ((blockLocal & 1) << 8) | threadIdx.x;
    const int f   = idx >> 1;
    const int h   = idx & 1;
    const int g   = (b << 9) | idx;

    const f32x4 lam  = ((const f32x4*)lambdas)[h];
    const f32x4 onem = 1.0f - lam;
    const int   t0   = chunk * TC;

    const float* fptr = features + (size_t)t0 * (BB * FF) + b * FF + f;
    const int*   rptr = resets + (size_t)t0 * BB + b;
    f32x4*       yptr = out4 + NGROUP + (size_t)t0 * NGROUP + g;

    f32x4 A = 1.0f;
    f32x4 s = 0.0f;
    #pragma unroll 8
    for (int t = 0; t < TC; ++t) {
        const float x = fptr[(size_t)t * (BB * FF)];
        const int   r = rptr[(size_t)t * BB];
        #pragma unroll
        for (int j = 0; j < 4; ++j) {
            const float Av = A[j] * lam[j];
            const float Ev = fmaf(lam[j], s[j], onem[j] * x);
            A[j] = r ? 0.0f : Av;
            s[j] = r ? x : Ev;
        }
        __builtin_nontemporal_store(s, yptr + (size_t)t * NGROUP);
    }
    wsA[(size_t)chunk * NGROUP + g] = A;
    wsE[(size_t)chunk * NGROUP + g] = s;
}

// Kernel 2: fold summaries -> true chunk-start state s0, then correct the
// pre-first-reset prefix of the chunk: y_t += lam^(t+1) * s0. Chunk NCHUNK-1
// also writes the final trace (first output in the concatenation).
template <int NCHUNK>
__global__ __launch_bounds__(256) void correct_kernel(
    const int*   __restrict__ resets,
    const float* __restrict__ carry,     // [B,F,L]
    const float* __restrict__ lambdas,
    const f32x4* __restrict__ wsA,
    const f32x4* __restrict__ wsE,
    f32x4*       __restrict__ out4)
{
    constexpr int TC = TT / NCHUNK;
    const int chunk      = blockIdx.x >> 6;
    const int blockLocal = blockIdx.x & 63;
    const int b   = blockLocal >> 1;
    const int idx = ((blockLocal & 1) << 8) | threadIdx.x;
    const int h   = idx & 1;
    const int g   = (b << 9) | idx;

    const f32x4 lam = ((const f32x4*)lambdas)[h];
    const int   t0  = chunk * TC;

    // Fold carry through chunks [0, chunk) -> true initial state s0.
    f32x4 s = ((const f32x4*)carry)[g];
    for (int cc = 0; cc < chunk; ++cc) {
        const f32x4 Ac = wsA[(size_t)cc * NGROUP + g];
        const f32x4 Ec = wsE[(size_t)cc * NGROUP + g];
        #pragma unroll
        for (int j = 0; j < 4; ++j) s[j] = fmaf(Ac[j], s[j], Ec[j]);
    }

    // Correct y_t for t before the chunk's first reset (r uniform per block,
    // so the break is wave-uniform -> no divergence).
    const int* rptr = resets + (size_t)t0 * BB + b;
    f32x4*     yptr = out4 + NGROUP + (size_t)t0 * NGROUP + g;
    f32x4 lamp = lam;  // lam^(t+1)
    for (int t = 0; t < TC; ++t) {
        if (rptr[(size_t)t * BB]) break;
        f32x4 y = yptr[(size_t)t * NGROUP];
        #pragma unroll
        for (int j = 0; j < 4; ++j) y[j] = fmaf(lamp[j], s[j], y[j]);
        yptr[(size_t)t * NGROUP] = y;
        #pragma unroll
        for (int j = 0; j < 4; ++j) lamp[j] *= lam[j];
    }

    if (chunk == NCHUNK - 1) {
        // final = A_last * s0 + E_last
        const f32x4 Ac = wsA[(size_t)chunk * NGROUP + g];
        const f32x4 Ec = wsE[(size_t)chunk * NGROUP + g];
        f32x4 fin;
        #pragma unroll
        for (int j = 0; j < 4; ++j) fin[j] = fmaf(Ac[j], s[j], Ec[j]);
        out4[g] = fin;  // final_trace region (first NCHAIN floats)
    }
}

// Fallback (ws too small): round-1 single-pass kernel, known correct.
__global__ __launch_bounds__(256) void trace_rnn_fallback(
    const float* __restrict__ features,
    const int*   __restrict__ resets,
    const float* __restrict__ carry,
    const float* __restrict__ lambdas,
    float*       __restrict__ out)
{
    const int b  = blockIdx.x >> 3;
    const int fl = ((blockIdx.x & 7) << 8) | threadIdx.x;
    const int f  = fl >> 3;
    const int l  = fl & 7;
    const int gid = (b << 11) | fl;

    const float lam  = lambdas[l];
    const float onem = 1.0f - lam;

    float trace = carry[gid];
    const float* fptr = features + b * FF + f;
    const int*   rptr = resets + b;
    float*       yptr = out + NCHAIN + gid;

    #pragma unroll 4
    for (int t = 0; t < TT; ++t) {
        const float x = fptr[(size_t)t * (BB * FF)];
        const int   r = rptr[(size_t)t * BB];
        const float v = fmaf(lam, trace, onem * x);
        trace = r ? x : v;
        yptr[(size_t)t * NCHAIN] = trace;
    }
    out[gid] = trace;
}

template <int NCHUNK>
static void launch_pair(const float* features, const int* resets,
                        const float* carry, const float* lambdas,
                        void* d_ws, float* out, hipStream_t stream) {
    f32x4* wsA = (f32x4*)d_ws;
    f32x4* wsE = wsA + (size_t)NCHUNK * NGROUP;
    const int grid = NCHUNK * 64;
    scan_write_kernel<NCHUNK><<<grid, 256, 0, stream>>>(
        features, resets, lambdas, wsA, wsE, (f32x4*)out);
    correct_kernel<NCHUNK><<<grid, 256, 0, stream>>>(
        resets, carry, lambdas, wsA, wsE, (f32x4*)out);
}

extern "C" void kernel_launch(void* const* d_in, const int* in_sizes, int n_in,
                              void* d_out, int out_size, void* d_ws, size_t ws_size,
                              hipStream_t stream) {
    const float* features = (const float*)d_in[0];
    const int*   resets   = (const int*)d_in[1];
    const float* carry    = (const float*)d_in[2];
    const float* lambdas  = (const float*)d_in[3];
    float* out = (float*)d_out;

    const size_t ws32 = (size_t)2 * 32 * NGROUP * sizeof(f32x4);  // 16 MB
    const size_t ws16 = (size_t)2 * 16 * NGROUP * sizeof(f32x4);  //  8 MB

    if (ws_size >= ws32) {
        launch_pair<32>(features, resets, carry, lambdas, d_ws, out, stream);
    } else if (ws_size >= ws16) {
        launch_pair<16>(features, resets, carry, lambdas, d_ws, out, stream);
    } else {
        trace_rnn_fallback<<<NCHAIN / 256, 256, 0, stream>>>(
            features, resets, carry, lambdas, out);
    }
}